// Round 1
// baseline (1048.962 us; speedup 1.0000x reference)
//
#include <hip/hip_runtime.h>
#include <hip/hip_bf16.h>

// Autoformer-style encoder on MI355X.
// B=8, L=3072, D=DM=CF=512, H=8, E=64, KSIZE=25, k_top=8.
//
// All GEMMs: bf16 hi/lo split (3-term) MFMA, fp32 accumulate -> ~fp32 accuracy.
// Autocorrelation: batched Q*K^T GEMM with wrapped-diagonal-sum epilogue
// (LDS bins + global atomics) -> mean_corr[B][L]; top-8 + softmax; 8-tap gather.
// Workspace: 16 MiB (weightsT + small) + 4 x 48 MiB fp32 activations = 208 MiB.

#define LQ 3072
#define DD 512
#define BB 8
#define MTOT (BB * LQ)   // 24576
#define KTOP 8
#define KSZ 25
#define KHALF 12

typedef __attribute__((ext_vector_type(4))) float f32x4;
typedef __attribute__((ext_vector_type(8))) short s16x8;
typedef __attribute__((ext_vector_type(4))) short s16x4;

__device__ __forceinline__ short f2bf(float x) {
  __hip_bfloat16 h = __float2bfloat16(x);
  return __builtin_bit_cast(short, h);
}
__device__ __forceinline__ float bf2f(short s) {
  __hip_bfloat16 h = __builtin_bit_cast(__hip_bfloat16, s);
  return __bfloat162float(h);
}

// ---------------------------------------------------------------------------
// Shared GEMM mainloop: C_tile += A[m0:m0+128, :K] * Bt[n0:n0+128, :K]^T
// computed as Ah*Bh + Ah*Bl + Al*Bh with on-the-fly fp32 -> bf16 hi/lo split.
// Tile 128x128, BK=32, 256 threads = 4 waves (2x2 of 64x64), 16x16x32 MFMA.
// LDS tiles padded to 40 shorts/row (80B) -> <=2-way bank aliasing (free).
// ---------------------------------------------------------------------------
#define LDT 40

__device__ __forceinline__ void stage_split(const float* __restrict__ src, int row0, int ld,
                                            int k0, short* __restrict__ Sh,
                                            short* __restrict__ Sl) {
  const int tid = threadIdx.x;
#pragma unroll
  for (int i = 0; i < 4; i++) {
    int cidx = tid + 256 * i;          // 0..1023 float4-chunks of the 128x32 tile
    int r = cidx >> 3;                 // row 0..127
    int kc = (cidx & 7) << 2;          // col 0,4,..,28
    const float* p = src + (size_t)(row0 + r) * ld + (k0 + kc);
    f32x4 v = *reinterpret_cast<const f32x4*>(p);
    s16x4 hv, lv;
#pragma unroll
    for (int j = 0; j < 4; j++) {
      float x = v[j];
      short h = f2bf(x);
      short lo = f2bf(x - bf2f(h));
      hv[j] = h;
      lv[j] = lo;
    }
    *reinterpret_cast<s16x4*>(&Sh[r * LDT + kc]) = hv;
    *reinterpret_cast<s16x4*>(&Sl[r * LDT + kc]) = lv;
  }
}

__device__ __forceinline__ void gemm_core(const float* __restrict__ A, const float* __restrict__ Bt,
                                          int lda, int ldb, int m0, int n0, int K,
                                          short* Ah, short* Al, short* Bh, short* Bl,
                                          f32x4 acc[4][4]) {
  const int tid = threadIdx.x;
  const int lane = tid & 63;
  const int w = tid >> 6;
  const int wr = w >> 1, wc = w & 1;
  const int q = lane >> 4, c = lane & 15;

#pragma unroll
  for (int m = 0; m < 4; m++)
#pragma unroll
    for (int n = 0; n < 4; n++) acc[m][n] = 0.f;

  for (int k0 = 0; k0 < K; k0 += 32) {
    __syncthreads();
    stage_split(A, m0, lda, k0, Ah, Al);
    stage_split(Bt, n0, ldb, k0, Bh, Bl);
    __syncthreads();
#pragma unroll
    for (int p = 0; p < 3; p++) {
      const short* Sa = (p == 2) ? Al : Ah;
      const short* Sb = (p == 1) ? Bl : Bh;
      s16x8 av[4], bv[4];
#pragma unroll
      for (int m = 0; m < 4; m++)
        av[m] = *reinterpret_cast<const s16x8*>(&Sa[(wr * 64 + m * 16 + c) * LDT + 8 * q]);
#pragma unroll
      for (int n = 0; n < 4; n++)
        bv[n] = *reinterpret_cast<const s16x8*>(&Sb[(wc * 64 + n * 16 + c) * LDT + 8 * q]);
#pragma unroll
      for (int m = 0; m < 4; m++)
#pragma unroll
        for (int n = 0; n < 4; n++)
          acc[m][n] = __builtin_amdgcn_mfma_f32_16x16x32_bf16(av[m], bv[n], acc[m][n], 0, 0, 0);
    }
  }
}

// C = A * Bt^T (+bias) (+res) (relu?) ; A[M,K], Bt[N,K], C[M,N]
__global__ void __launch_bounds__(256, 2)
gemm_split_nt(const float* __restrict__ A, const float* __restrict__ Bt,
              const float* __restrict__ bias, const float* __restrict__ res,
              float* __restrict__ C, int N, int K, int lda, int ldb, int relu) {
  __shared__ short Ah[128 * LDT], Al[128 * LDT], Bh[128 * LDT], Bl[128 * LDT];
  const int m0 = blockIdx.y * 128, n0 = blockIdx.x * 128;
  f32x4 acc[4][4];
  gemm_core(A, Bt, lda, ldb, m0, n0, K, Ah, Al, Bh, Bl, acc);

  const int tid = threadIdx.x, lane = tid & 63, w = tid >> 6;
  const int wr = w >> 1, wc = w & 1, q = lane >> 4, c = lane & 15;
#pragma unroll
  for (int m = 0; m < 4; m++)
#pragma unroll
    for (int n = 0; n < 4; n++) {
      int col = n0 + wc * 64 + n * 16 + c;
      float badd = bias ? bias[col] : 0.f;
#pragma unroll
      for (int r = 0; r < 4; r++) {
        int row = m0 + wr * 64 + m * 16 + 4 * q + r;
        size_t off = (size_t)row * N + col;
        float val = acc[m][n][r] + badd;
        if (res) val += res[off];
        if (relu) val = fmaxf(val, 0.f);
        C[off] = val;
      }
    }
}

// Batched Q*K^T with wrapped-diagonal reduction:
// mean_corr[b, (t-s) mod L] += sum over tile of q[b,t,:].k[b,s,:]
__global__ void __launch_bounds__(256, 2)
corr_gemm(const float* __restrict__ Q, const float* __restrict__ Kk, float* __restrict__ mc) {
  __shared__ short Ah[128 * LDT], Al[128 * LDT], Bh[128 * LDT], Bl[128 * LDT];
  __shared__ float bins[256];
  const int b = blockIdx.z;
  const int m0 = blockIdx.y * 128, n0 = blockIdx.x * 128;
  const float* A = Q + (size_t)b * LQ * DD;
  const float* Bt = Kk + (size_t)b * LQ * DD;

  bins[threadIdx.x] = 0.f;  // visible after gemm_core's first barrier

  f32x4 acc[4][4];
  gemm_core(A, Bt, DD, DD, m0, n0, DD, Ah, Al, Bh, Bl, acc);

  const int tid = threadIdx.x, lane = tid & 63, w = tid >> 6;
  const int wr = w >> 1, wc = w & 1, q = lane >> 4, c = lane & 15;

  // per-lane pre-reduction: tau = 128*(by-bx) + 64*(wr-wc) + 16*(m-n) + 4q + r - c
  float psum[7][4];
#pragma unroll
  for (int d = 0; d < 7; d++)
#pragma unroll
    for (int r = 0; r < 4; r++) psum[d][r] = 0.f;
#pragma unroll
  for (int m = 0; m < 4; m++)
#pragma unroll
    for (int n = 0; n < 4; n++) {
      int d = m - n + 3;
#pragma unroll
      for (int r = 0; r < 4; r++) psum[d][r] += acc[m][n][r];
    }

  __syncthreads();
  const int lanebase = 64 * (wr - wc) + 4 * q - c + 127;  // +16*(d-3)+r stays in [0,254]
#pragma unroll
  for (int d = 0; d < 7; d++)
#pragma unroll
    for (int r = 0; r < 4; r++) atomicAdd(&bins[lanebase + 16 * (d - 3) + r], psum[d][r]);
  __syncthreads();

  if (tid < 255) {
    int tau = 128 * ((int)blockIdx.y - (int)blockIdx.x) + tid - 127;
    tau = ((tau % LQ) + LQ) % LQ;
    atomicAdd(&mc[b * LQ + tau], bins[tid]);
  }
}

// ---------------------------------------------------------------------------
// Elementwise / small kernels
// ---------------------------------------------------------------------------
struct P8 {
  const float* p[8];
};

__global__ void transpose_weights(P8 srcs, float* __restrict__ dst) {
  __shared__ float t[32][33];
  const int i = blockIdx.z;
  const float* src = srcs.p[i];
  float* d = dst + (size_t)i * DD * DD;
  const int x0 = blockIdx.x * 32, y0 = blockIdx.y * 32;
  const int tx = threadIdx.x, ty = threadIdx.y;  // (32,8)
#pragma unroll
  for (int j = 0; j < 4; j++) t[ty + 8 * j][tx] = src[(size_t)(y0 + ty + 8 * j) * DD + x0 + tx];
  __syncthreads();
#pragma unroll
  for (int j = 0; j < 4; j++) d[(size_t)(x0 + ty + 8 * j) * DD + (y0 + tx)] = t[tx][ty + 8 * j];
}

__global__ void zero_f32(float* __restrict__ p, int n) {
  int i = blockIdx.x * blockDim.x + threadIdx.x;
  if (i < n) p[i] = 0.f;
}

// per-batch top-8 (low-index tie-break, matching lax.top_k) + softmax
__global__ void topk_softmax(const float* __restrict__ mc, int* __restrict__ delays,
                             float* __restrict__ weights) {
  const int b = blockIdx.x, tid = threadIdx.x;
  __shared__ float vals[LQ];
  __shared__ float rv[256];
  __shared__ int ri[256];
  __shared__ float topv[KTOP];
  __shared__ int topi[KTOP];
  for (int i = tid; i < LQ; i += 256) vals[i] = mc[b * LQ + i] * (1.0f / 512.0f);
  __syncthreads();
  for (int t = 0; t < KTOP; t++) {
    float bv = -1e30f;
    int bi = 0x7fffffff;
    for (int i = tid; i < LQ; i += 256) {
      float v = vals[i];
      if (v > bv || (v == bv && i < bi)) { bv = v; bi = i; }
    }
    rv[tid] = bv;
    ri[tid] = bi;
    __syncthreads();
    for (int s = 128; s > 0; s >>= 1) {
      if (tid < s) {
        if (rv[tid + s] > rv[tid] || (rv[tid + s] == rv[tid] && ri[tid + s] < ri[tid])) {
          rv[tid] = rv[tid + s];
          ri[tid] = ri[tid + s];
        }
      }
      __syncthreads();
    }
    if (tid == 0) {
      topv[t] = rv[0];
      topi[t] = ri[0];
      vals[ri[0]] = -1e38f;
    }
    __syncthreads();
  }
  if (tid == 0) {
    float mx = topv[0];
#pragma unroll
    for (int i = 1; i < KTOP; i++) mx = fmaxf(mx, topv[i]);
    float e[KTOP], s = 0.f;
#pragma unroll
    for (int i = 0; i < KTOP; i++) {
      e[i] = expf(topv[i] - mx);
      s += e[i];
    }
#pragma unroll
    for (int i = 0; i < KTOP; i++) {
      weights[b * KTOP + i] = e[i] / s;
      delays[b * KTOP + i] = topi[i];
    }
  }
}

// attn[b,l,:] = sum_i w[b,i] * v[b,(l+delay_i)%L,:]
__global__ void attn_gather(const float* __restrict__ v, const int* __restrict__ delays,
                            const float* __restrict__ w, float* __restrict__ out) {
  int idx = blockIdx.x * blockDim.x + threadIdx.x;  // float4 units
  const int total = BB * LQ * (DD / 4);
  if (idx >= total) return;
  int b = idx / (LQ * (DD / 4));
  int rem = idx % (LQ * (DD / 4));
  int l = rem / (DD / 4), dq = rem % (DD / 4);
  f32x4 acc = 0.f;
#pragma unroll
  for (int i = 0; i < KTOP; i++) {
    int d = delays[b * KTOP + i];
    float wi = w[b * KTOP + i];
    int ls = (l + d) % LQ;
    f32x4 vv = *reinterpret_cast<const f32x4*>(v + ((size_t)b * LQ + ls) * DD + dq * 4);
    acc += vv * wi;
  }
  *reinterpret_cast<f32x4*>(out + ((size_t)b * LQ + l) * DD + dq * 4) = acc;
}

// seasonal = x - movavg_25(x), TF-SAME (count excludes padding)
__global__ void decomp_kernel(const float* __restrict__ x, float* __restrict__ out) {
  __shared__ float tile[64 + 2 * KHALF][64];
  const int l0 = blockIdx.x * 64, d0 = blockIdx.y * 64, b = blockIdx.z;
  const int tx = threadIdx.x & 63, ty = threadIdx.x >> 6;  // 4 row-groups
  const float* xb = x + (size_t)b * LQ * DD;
  for (int r = ty; r < 64 + 2 * KHALF; r += 4) {
    int l = l0 + r - KHALF;
    tile[r][tx] = (l >= 0 && l < LQ) ? xb[(size_t)l * DD + d0 + tx] : 0.f;
  }
  __syncthreads();
#pragma unroll
  for (int j = 0; j < 16; j++) {
    int lr = ty + 4 * j;  // 0..63
    int l = l0 + lr;
    float s = 0.f;
#pragma unroll
    for (int t = 0; t < KSZ; t++) s += tile[lr + t][tx];
    int lo = max(0, l - KHALF), hi = min(LQ - 1, l + KHALF);
    float cnt = (float)(hi - lo + 1);
    out[((size_t)b * LQ + l) * DD + d0 + tx] = tile[lr + KHALF][tx] - s / cnt;
  }
}

// ---------------------------------------------------------------------------
extern "C" void kernel_launch(void* const* d_in, const int* in_sizes, int n_in,
                              void* d_out, int out_size, void* d_ws, size_t ws_size,
                              hipStream_t stream) {
  const float* inputs = (const float*)d_in[0];
  const float* b_res = (const float*)d_in[2];
  const float* b_in = (const float*)d_in[4];
  const float* bq = (const float*)d_in[6];
  const float* bk = (const float*)d_in[8];
  const float* bv = (const float*)d_in[10];
  const float* bo = (const float*)d_in[12];
  float* outp = (float*)d_out;

  // workspace layout (needs ~208 MiB)
  float* WT = (float*)d_ws;                     // 8 x 512 x 512 transposed weights
  float* mean_corr = WT + 8 * DD * DD;          // 8*3072
  int* delays = (int*)(mean_corr + BB * LQ);    // 64
  float* weights = (float*)(delays + 64);       // 64
  const size_t FSZ = (size_t)MTOT * DD;         // 12,582,912 floats
  float* F0 = (float*)((char*)d_ws + (16u << 20));
  float* F1 = F0 + FSZ;
  float* F2 = F1 + FSZ;
  float* F3 = F2 + FSZ;

  P8 wp;
  wp.p[0] = (const float*)d_in[1];   // W_res
  wp.p[1] = (const float*)d_in[3];   // W_in
  wp.p[2] = (const float*)d_in[5];   // Wq
  wp.p[3] = (const float*)d_in[7];   // Wk
  wp.p[4] = (const float*)d_in[9];   // Wv
  wp.p[5] = (const float*)d_in[11];  // Wo
  wp.p[6] = (const float*)d_in[13];  // Wc1
  wp.p[7] = (const float*)d_in[14];  // Wc2

  transpose_weights<<<dim3(16, 16, 8), dim3(32, 8), 0, stream>>>(wp, WT);

  const dim3 gg(DD / 128, MTOT / 128);  // (4, 192)
  // proj = inputs @ W_res + b_res
  gemm_split_nt<<<gg, 256, 0, stream>>>(inputs, WT + 0 * DD * DD, b_res, nullptr, F0, DD, DD, DD, DD, 0);
  // x1 = proj @ W_in + b_in
  gemm_split_nt<<<gg, 256, 0, stream>>>(F0, WT + 1 * DD * DD, b_in, nullptr, F1, DD, DD, DD, DD, 0);
  // q, k
  gemm_split_nt<<<gg, 256, 0, stream>>>(F1, WT + 2 * DD * DD, bq, nullptr, F2, DD, DD, DD, DD, 0);
  gemm_split_nt<<<gg, 256, 0, stream>>>(F1, WT + 3 * DD * DD, bk, nullptr, F3, DD, DD, DD, DD, 0);
  // mean_corr = diag-sums of Q K^T
  zero_f32<<<(BB * LQ + 255) / 256, 256, 0, stream>>>(mean_corr, BB * LQ);
  corr_gemm<<<dim3(LQ / 128, LQ / 128, BB), 256, 0, stream>>>(F2, F3, mean_corr);
  topk_softmax<<<BB, 256, 0, stream>>>(mean_corr, delays, weights);
  // v (overwrites q)
  gemm_split_nt<<<gg, 256, 0, stream>>>(F1, WT + 4 * DD * DD, bv, nullptr, F2, DD, DD, DD, DD, 0);
  // attn gather (overwrites k)
  attn_gather<<<(BB * LQ * (DD / 4) + 255) / 256, 256, 0, stream>>>(F2, delays, weights, F3);
  // x2 = attn @ Wo + bo + proj   (overwrites x1)
  gemm_split_nt<<<gg, 256, 0, stream>>>(F3, WT + 5 * DD * DD, bo, F0, F1, DD, DD, DD, DD, 0);
  // seasonal = decomp(x2)
  decomp_kernel<<<dim3(LQ / 64, DD / 64, BB), 256, 0, stream>>>(F1, F2);
  // y1 = relu(seasonal @ Wc1)
  gemm_split_nt<<<gg, 256, 0, stream>>>(F2, WT + 6 * DD * DD, nullptr, nullptr, F3, DD, DD, DD, DD, 1);
  // y2 = y1 @ Wc2
  gemm_split_nt<<<gg, 256, 0, stream>>>(F3, WT + 7 * DD * DD, nullptr, nullptr, F1, DD, DD, DD, DD, 0);
  // out = decomp(y2)
  decomp_kernel<<<dim3(LQ / 64, DD / 64, BB), 256, 0, stream>>>(F1, outp);
}

// Round 2
// 1014.508 us; speedup vs baseline: 1.0340x; 1.0340x over previous
//
#include <hip/hip_runtime.h>
#include <hip/hip_bf16.h>

// Autoformer encoder, MI355X. Round 2: m97-style GEMM structure.
// - All operands pre-split to bf16 hi/lo global arrays (fused into producer epilogues).
// - GEMM main loop: global_load_lds(16B) -> swizzled ds_read_b128 -> 48 MFMA / K-step.
// - 3-term split (AhBh+AhBl+AlBh) = ~fp32 accuracy, 3:1 MFMA:ds_read density.
// - LDS: row-pair-packed 128B lines, XOR swizzle (((r&1)<<2)|q)^(L&7); linear LDS dest +
//   inverse-swizzled per-lane GLOBAL source (guide rule 21) -> <=2-way bank access (free).
// Workspace: 8MB weights h/l + misc + 4 x 48MB regions = 208MiB (proven size).

#define LQ 3072
#define DD 512
#define BB 8
#define MTOT (BB * LQ)   // 24576
#define KTOP 8
#define KSZ 25
#define KHALF 12
#define KK 512           // K of every GEMM
#define KB (KK * 2)      // bf16 row bytes = 1024

typedef unsigned short ushort_t;
typedef __attribute__((ext_vector_type(4))) float f32x4;
typedef __attribute__((ext_vector_type(8))) short s16x8;
typedef __attribute__((ext_vector_type(4))) short s16x4;

typedef __attribute__((address_space(1))) unsigned int u32_g;
typedef __attribute__((address_space(3))) unsigned int u32_l;

__device__ __forceinline__ ushort_t f2bfbits(float x) {
  __hip_bfloat16 h = __float2bfloat16(x);
  return __builtin_bit_cast(unsigned short, h);
}
__device__ __forceinline__ float bfbits2f(ushort_t s) {
  __hip_bfloat16 h = __builtin_bit_cast(__hip_bfloat16, (unsigned short)s);
  return __bfloat162float(h);
}

__device__ __forceinline__ void gload_lds16(const void* g, void* l) {
  __builtin_amdgcn_global_load_lds((const u32_g*)g, (u32_l*)l, 16, 0, 0);
}

// ---------------------------------------------------------------------------
// Core: acc[4][4] (64x64 per wave, 2x2 waves = 128x128 block) over K=512.
// A as (Ah,Al) bf16 [rows x 512], B as (Bh,Bl) bf16 [rows x 512] (row = out col).
// 3-term MFMA. LDS tiles: w0=Ah, w1=Al, w2=Bh, w3=Bl, each 8KB (128 rows x 64B,
// pair-packed into 64 lines x 128B, slot-swizzled).
// ---------------------------------------------------------------------------
__device__ __forceinline__ void gemm3_core(
    const ushort_t* __restrict__ Ah, const ushort_t* __restrict__ Al,
    const ushort_t* __restrict__ Bh, const ushort_t* __restrict__ Bl,
    int arow0, int brow0, char* lds, f32x4 acc[4][4]) {
  const int tid = threadIdx.x, lane = tid & 63, w = tid >> 6;
  const int wr = w >> 1, wc = w & 1;
  const int c = lane & 15, qd = lane >> 4;

  // --- staging setup: wave w owns tile w ---
  const ushort_t* ssrc = (w == 0) ? Ah : (w == 1) ? Al : (w == 2) ? Bh : Bl;
  const int srow0 = (w < 2) ? arow0 : brow0;
  const int L0 = lane >> 3, sl = lane & 7;
  const int u = sl ^ L0;  // line-local swizzle: L&7 == L0 for every wave-load
  const char* gbase =
      (const char*)ssrc + (size_t)(srow0 + 2 * L0 + (u >> 2)) * KB + (u & 3) * 16;
  char* ldsT = lds + w * 8192;  // wave-uniform

  // --- fragment LDS byte offsets (constant across K loop) ---
  int aoff[4], boff[4];
#pragma unroll
  for (int m = 0; m < 4; m++) {
    int r = wr * 64 + m * 16 + c;
    int L = r >> 1;
    aoff[m] = L * 128 + (((((r & 1) << 2) | qd) ^ (L & 7)) << 4);
    r = wc * 64 + m * 16 + c;
    L = r >> 1;
    boff[m] = 16384 + L * 128 + (((((r & 1) << 2) | qd) ^ (L & 7)) << 4);
  }

#pragma unroll
  for (int m = 0; m < 4; m++)
#pragma unroll
    for (int n = 0; n < 4; n++) acc[m][n] = 0.f;

  for (int k0 = 0; k0 < KK; k0 += 32) {
    __syncthreads();  // previous tile fully consumed
    const char* g = gbase + k0 * 2;
#pragma unroll
    for (int i = 0; i < 8; i++) gload_lds16(g + (size_t)i * (16 * KB), ldsT + i * 1024);
    __syncthreads();  // staging drained (compiler emits vmcnt(0) before barrier)

    s16x8 ah[4], al[4];
#pragma unroll
    for (int m = 0; m < 4; m++) {
      ah[m] = *(const s16x8*)(lds + aoff[m]);
      al[m] = *(const s16x8*)(lds + 8192 + aoff[m]);
    }
#pragma unroll
    for (int n = 0; n < 4; n++) {
      s16x8 bh = *(const s16x8*)(lds + boff[n]);
      s16x8 bl = *(const s16x8*)(lds + 8192 + boff[n]);
#pragma unroll
      for (int m = 0; m < 4; m++) {
        acc[m][n] = __builtin_amdgcn_mfma_f32_16x16x32_bf16(ah[m], bh, acc[m][n], 0, 0, 0);
        acc[m][n] = __builtin_amdgcn_mfma_f32_16x16x32_bf16(ah[m], bl, acc[m][n], 0, 0, 0);
        acc[m][n] = __builtin_amdgcn_mfma_f32_16x16x32_bf16(al[m], bh, acc[m][n], 0, 0, 0);
      }
    }
  }
}

// C = A*B^T variants. OUTMODE: 0 = fp32, 1 = bf16 h/l. RESMODE: 0 none, 1 = h/l residual.
template <int OUTMODE, int RESMODE, int RELU>
__global__ __launch_bounds__(256, 3) void gemm_bf16x3(
    const ushort_t* __restrict__ Ah, const ushort_t* __restrict__ Al,
    const ushort_t* __restrict__ Bh, const ushort_t* __restrict__ Bl,
    const float* __restrict__ bias,
    const ushort_t* __restrict__ resH, const ushort_t* __restrict__ resL,
    float* __restrict__ outF, ushort_t* __restrict__ outH, ushort_t* __restrict__ outL) {
  __shared__ alignas(16) char lds[32768];
  const int m0 = blockIdx.y * 128, n0 = blockIdx.x * 128;
  f32x4 acc[4][4];
  gemm3_core(Ah, Al, Bh, Bl, m0, n0, lds, acc);

  const int tid = threadIdx.x, lane = tid & 63, w = tid >> 6;
  const int wr = w >> 1, wc = w & 1, qd = lane >> 4, c = lane & 15;
#pragma unroll
  for (int m = 0; m < 4; m++)
#pragma unroll
    for (int n = 0; n < 4; n++) {
      int col = n0 + wc * 64 + n * 16 + c;
      float badd = bias ? bias[col] : 0.f;
#pragma unroll
      for (int r = 0; r < 4; r++) {
        int row = m0 + wr * 64 + m * 16 + 4 * qd + r;
        size_t off = (size_t)row * DD + col;
        float val = acc[m][n][r] + badd;
        if (RESMODE == 1) val += bfbits2f(resH[off]) + bfbits2f(resL[off]);
        if (RELU) val = fmaxf(val, 0.f);
        if (OUTMODE == 0) {
          outF[off] = val;
        } else {
          ushort_t h = f2bfbits(val);
          outH[off] = h;
          outL[off] = f2bfbits(val - bfbits2f(h));
        }
      }
    }
}

// Batched Q*K^T, wrapped-diagonal-sum epilogue -> mean_corr (x512 scale applied later).
__global__ __launch_bounds__(256, 3) void corr_gemm(
    const ushort_t* __restrict__ Qh, const ushort_t* __restrict__ Ql,
    const ushort_t* __restrict__ Kh, const ushort_t* __restrict__ Kl,
    float* __restrict__ mc) {
  __shared__ alignas(16) char lds[32768];
  __shared__ float bins[256];
  const int b = blockIdx.z;
  const int m0 = blockIdx.y * 128, n0 = blockIdx.x * 128;
  bins[threadIdx.x] = 0.f;  // ordered by first barrier inside core
  f32x4 acc[4][4];
  gemm3_core(Qh, Ql, Kh, Kl, b * LQ + m0, b * LQ + n0, lds, acc);

  const int tid = threadIdx.x, lane = tid & 63, w = tid >> 6;
  const int wr = w >> 1, wc = w & 1, qd = lane >> 4, c = lane & 15;

  float psum[7][4];
#pragma unroll
  for (int d = 0; d < 7; d++)
#pragma unroll
    for (int r = 0; r < 4; r++) psum[d][r] = 0.f;
#pragma unroll
  for (int m = 0; m < 4; m++)
#pragma unroll
    for (int n = 0; n < 4; n++) {
      int d = m - n + 3;
#pragma unroll
      for (int r = 0; r < 4; r++) psum[d][r] += acc[m][n][r];
    }

  __syncthreads();
  const int lanebase = 64 * (wr - wc) + 4 * qd - c + 127;
#pragma unroll
  for (int d = 0; d < 7; d++)
#pragma unroll
    for (int r = 0; r < 4; r++) atomicAdd(&bins[lanebase + 16 * (d - 3) + r], psum[d][r]);
  __syncthreads();

  if (tid < 255) {
    int tau = 128 * ((int)blockIdx.y - (int)blockIdx.x) + tid - 127;
    tau = ((tau % LQ) + LQ) % LQ;
    atomicAdd(&mc[b * LQ + tau], bins[tid]);
  }
}

// ---------------------------------------------------------------------------
// Small kernels
// ---------------------------------------------------------------------------
struct P8 {
  const float* p[8];
};

__global__ void transpose_split(P8 srcs, ushort_t* __restrict__ dH, ushort_t* __restrict__ dL) {
  __shared__ float t[32][33];
  const int i = blockIdx.z;
  const float* src = srcs.p[i];
  const size_t base = (size_t)i * DD * DD;
  const int x0 = blockIdx.x * 32, y0 = blockIdx.y * 32;
  const int tx = threadIdx.x, ty = threadIdx.y;  // (32,8)
#pragma unroll
  for (int j = 0; j < 4; j++) t[ty + 8 * j][tx] = src[(size_t)(y0 + ty + 8 * j) * DD + x0 + tx];
  __syncthreads();
#pragma unroll
  for (int j = 0; j < 4; j++) {
    float v = t[tx][ty + 8 * j];
    size_t o = base + (size_t)(x0 + ty + 8 * j) * DD + (y0 + tx);
    ushort_t h = f2bfbits(v);
    dH[o] = h;
    dL[o] = f2bfbits(v - bfbits2f(h));
  }
}

__global__ void split_f32(const float* __restrict__ x, ushort_t* __restrict__ h,
                          ushort_t* __restrict__ l, int n4) {
  int i = blockIdx.x * blockDim.x + threadIdx.x;
  if (i >= n4) return;
  f32x4 v = *reinterpret_cast<const f32x4*>(x + (size_t)i * 4);
  s16x4 hv, lv;
#pragma unroll
  for (int j = 0; j < 4; j++) {
    ushort_t hb = f2bfbits(v[j]);
    hv[j] = (short)hb;
    lv[j] = (short)f2bfbits(v[j] - bfbits2f(hb));
  }
  *reinterpret_cast<s16x4*>(h + (size_t)i * 4) = hv;
  *reinterpret_cast<s16x4*>(l + (size_t)i * 4) = lv;
}

__global__ void zero_f32(float* __restrict__ p, int n) {
  int i = blockIdx.x * blockDim.x + threadIdx.x;
  if (i < n) p[i] = 0.f;
}

__global__ void topk_softmax(const float* __restrict__ mc, int* __restrict__ delays,
                             float* __restrict__ weights) {
  const int b = blockIdx.x, tid = threadIdx.x;
  __shared__ float vals[LQ];
  __shared__ float rv[256];
  __shared__ int ri[256];
  __shared__ float topv[KTOP];
  __shared__ int topi[KTOP];
  for (int i = tid; i < LQ; i += 256) vals[i] = mc[b * LQ + i] * (1.0f / 512.0f);
  __syncthreads();
  for (int t = 0; t < KTOP; t++) {
    float bv = -1e30f;
    int bi = 0x7fffffff;
    for (int i = tid; i < LQ; i += 256) {
      float v = vals[i];
      if (v > bv || (v == bv && i < bi)) { bv = v; bi = i; }
    }
    rv[tid] = bv;
    ri[tid] = bi;
    __syncthreads();
    for (int s = 128; s > 0; s >>= 1) {
      if (tid < s) {
        if (rv[tid + s] > rv[tid] || (rv[tid + s] == rv[tid] && ri[tid + s] < ri[tid])) {
          rv[tid] = rv[tid + s];
          ri[tid] = ri[tid + s];
        }
      }
      __syncthreads();
    }
    if (tid == 0) {
      topv[t] = rv[0];
      topi[t] = ri[0];
      vals[ri[0]] = -1e38f;
    }
    __syncthreads();
  }
  if (tid == 0) {
    float mx = topv[0];
#pragma unroll
    for (int i = 1; i < KTOP; i++) mx = fmaxf(mx, topv[i]);
    float e[KTOP], s = 0.f;
#pragma unroll
    for (int i = 0; i < KTOP; i++) {
      e[i] = expf(topv[i] - mx);
      s += e[i];
    }
#pragma unroll
    for (int i = 0; i < KTOP; i++) {
      weights[b * KTOP + i] = e[i] / s;
      delays[b * KTOP + i] = topi[i];
    }
  }
}

// attn[b,l,:] = sum_i w[b,i] * v[b,(l+delay_i)%L,:]  -> bf16 h/l output
__global__ void attn_gather(const float* __restrict__ v, const int* __restrict__ delays,
                            const float* __restrict__ w, ushort_t* __restrict__ oH,
                            ushort_t* __restrict__ oL) {
  int idx = blockIdx.x * blockDim.x + threadIdx.x;
  const int total = BB * LQ * (DD / 4);
  if (idx >= total) return;
  int b = idx / (LQ * (DD / 4));
  int rem = idx % (LQ * (DD / 4));
  int l = rem / (DD / 4), dq = rem % (DD / 4);
  f32x4 acc = 0.f;
#pragma unroll
  for (int i = 0; i < KTOP; i++) {
    int d = delays[b * KTOP + i];
    float wi = w[b * KTOP + i];
    int ls = (l + d) % LQ;
    f32x4 vv = *reinterpret_cast<const f32x4*>(v + ((size_t)b * LQ + ls) * DD + dq * 4);
    acc += vv * wi;
  }
  size_t o = ((size_t)b * LQ + l) * DD + dq * 4;
  s16x4 hv, lv;
#pragma unroll
  for (int j = 0; j < 4; j++) {
    ushort_t hb = f2bfbits(acc[j]);
    hv[j] = (short)hb;
    lv[j] = (short)f2bfbits(acc[j] - bfbits2f(hb));
  }
  *reinterpret_cast<s16x4*>(oH + o) = hv;
  *reinterpret_cast<s16x4*>(oL + o) = lv;
}

// seasonal = x - movavg_25(x), TF-SAME counts. OUT_HL: 1 -> bf16 h/l, 0 -> fp32.
template <int OUT_HL>
__global__ void decomp_kernel(const float* __restrict__ x, float* __restrict__ outF,
                              ushort_t* __restrict__ outH, ushort_t* __restrict__ outL) {
  __shared__ float tile[64 + 2 * KHALF][64];
  const int l0 = blockIdx.x * 64, d0 = blockIdx.y * 64, b = blockIdx.z;
  const int tx = threadIdx.x & 63, ty = threadIdx.x >> 6;
  const float* xb = x + (size_t)b * LQ * DD;
  for (int r = ty; r < 64 + 2 * KHALF; r += 4) {
    int l = l0 + r - KHALF;
    tile[r][tx] = (l >= 0 && l < LQ) ? xb[(size_t)l * DD + d0 + tx] : 0.f;
  }
  __syncthreads();
#pragma unroll
  for (int j = 0; j < 16; j++) {
    int lr = ty + 4 * j;
    int l = l0 + lr;
    float s = 0.f;
#pragma unroll
    for (int t = 0; t < KSZ; t++) s += tile[lr + t][tx];
    int lo = max(0, l - KHALF), hi = min(LQ - 1, l + KHALF);
    float val = tile[lr + KHALF][tx] - s / (float)(hi - lo + 1);
    size_t o = ((size_t)b * LQ + l) * DD + d0 + tx;
    if (OUT_HL) {
      ushort_t h = f2bfbits(val);
      outH[o] = h;
      outL[o] = f2bfbits(val - bfbits2f(h));
    } else {
      outF[o] = val;
    }
  }
}

// ---------------------------------------------------------------------------
extern "C" void kernel_launch(void* const* d_in, const int* in_sizes, int n_in,
                              void* d_out, int out_size, void* d_ws, size_t ws_size,
                              hipStream_t stream) {
  const float* inputs = (const float*)d_in[0];
  const float* b_res = (const float*)d_in[2];
  const float* b_in = (const float*)d_in[4];
  const float* bq = (const float*)d_in[6];
  const float* bk = (const float*)d_in[8];
  const float* bv = (const float*)d_in[10];
  const float* bo = (const float*)d_in[12];
  float* outp = (float*)d_out;

  // workspace: [0,4M) WTh, [4M,8M) WTl, [8M,+) mc/delays/weights, [16M..208M) R0..R3
  char* ws = (char*)d_ws;
  ushort_t* WTh = (ushort_t*)ws;
  ushort_t* WTl = (ushort_t*)(ws + (4u << 20));
  float* mean_corr = (float*)(ws + (8u << 20));
  int* delays = (int*)(ws + (8u << 20) + 98304);
  float* weights = (float*)(ws + (8u << 20) + 98304 + 256);
  char* R0 = ws + (16u << 20);
  char* R1 = ws + (64u << 20);
  char* R2 = ws + (112u << 20);
  char* R3 = ws + (160u << 20);
  const size_t HALF = 24u << 20;  // h at R, l at R+24MB
  ushort_t *R0h = (ushort_t*)R0, *R0l = (ushort_t*)(R0 + HALF);
  ushort_t *R1h = (ushort_t*)R1, *R1l = (ushort_t*)(R1 + HALF);
  ushort_t *R2h = (ushort_t*)R2, *R2l = (ushort_t*)(R2 + HALF);
  ushort_t *R3h = (ushort_t*)R3, *R3l = (ushort_t*)(R3 + HALF);
  const size_t WS1 = (size_t)DD * DD;  // 262144 elements per weight matrix

  P8 wp;
  wp.p[0] = (const float*)d_in[1];   // W_res
  wp.p[1] = (const float*)d_in[3];   // W_in
  wp.p[2] = (const float*)d_in[5];   // Wq
  wp.p[3] = (const float*)d_in[7];   // Wk
  wp.p[4] = (const float*)d_in[9];   // Wv
  wp.p[5] = (const float*)d_in[11];  // Wo
  wp.p[6] = (const float*)d_in[13];  // Wc1
  wp.p[7] = (const float*)d_in[14];  // Wc2

  transpose_split<<<dim3(16, 16, 8), dim3(32, 8), 0, stream>>>(wp, WTh, WTl);
  split_f32<<<(MTOT * DD / 4 + 255) / 256, 256, 0, stream>>>(inputs, R1h, R1l, MTOT * DD / 4);

  const dim3 G(DD / 128, MTOT / 128);  // (4, 192)
  // proj = in @ W_res + b_res  -> R0 h/l
  gemm_bf16x3<1, 0, 0><<<G, 256, 0, stream>>>(R1h, R1l, WTh + 0 * WS1, WTl + 0 * WS1, b_res,
                                              nullptr, nullptr, nullptr, R0h, R0l);
  // x1 = proj @ W_in + b_in  -> R1 h/l (inputs split dead)
  gemm_bf16x3<1, 0, 0><<<G, 256, 0, stream>>>(R0h, R0l, WTh + 1 * WS1, WTl + 1 * WS1, b_in,
                                              nullptr, nullptr, nullptr, R1h, R1l);
  // q -> R2 h/l ; k -> R3 h/l
  gemm_bf16x3<1, 0, 0><<<G, 256, 0, stream>>>(R1h, R1l, WTh + 2 * WS1, WTl + 2 * WS1, bq,
                                              nullptr, nullptr, nullptr, R2h, R2l);
  gemm_bf16x3<1, 0, 0><<<G, 256, 0, stream>>>(R1h, R1l, WTh + 3 * WS1, WTl + 3 * WS1, bk,
                                              nullptr, nullptr, nullptr, R3h, R3l);
  // mean_corr
  zero_f32<<<(BB * LQ + 255) / 256, 256, 0, stream>>>(mean_corr, BB * LQ);
  corr_gemm<<<dim3(LQ / 128, LQ / 128, BB), 256, 0, stream>>>(R2h, R2l, R3h, R3l, mean_corr);
  topk_softmax<<<BB, 256, 0, stream>>>(mean_corr, delays, weights);
  // v -> R2 fp32 (q dead)
  gemm_bf16x3<0, 0, 0><<<G, 256, 0, stream>>>(R1h, R1l, WTh + 4 * WS1, WTl + 4 * WS1, bv,
                                              nullptr, nullptr, (float*)R2, nullptr, nullptr);
  // attn -> R3 h/l (k dead)
  attn_gather<<<(BB * LQ * (DD / 4) + 255) / 256, 256, 0, stream>>>((const float*)R2, delays,
                                                                    weights, R3h, R3l);
  // x2 = attn @ Wo + bo + proj -> R1 fp32 (x1 dead)
  gemm_bf16x3<0, 1, 0><<<G, 256, 0, stream>>>(R3h, R3l, WTh + 5 * WS1, WTl + 5 * WS1, bo,
                                              R0h, R0l, (float*)R1, nullptr, nullptr);
  // seasonal -> R0 h/l (proj dead)
  decomp_kernel<1><<<dim3(LQ / 64, DD / 64, BB), 256, 0, stream>>>((const float*)R1, nullptr,
                                                                   R0h, R0l);
  // y1 = relu(seasonal @ Wc1) -> R2 h/l (v dead)
  gemm_bf16x3<1, 0, 1><<<G, 256, 0, stream>>>(R0h, R0l, WTh + 6 * WS1, WTl + 6 * WS1, nullptr,
                                              nullptr, nullptr, nullptr, R2h, R2l);
  // y2 = y1 @ Wc2 -> R1 fp32 (x2 dead)
  gemm_bf16x3<0, 0, 0><<<G, 256, 0, stream>>>(R2h, R2l, WTh + 7 * WS1, WTl + 7 * WS1, nullptr,
                                              nullptr, nullptr, (float*)R1, nullptr, nullptr);
  // out = decomp(y2)
  decomp_kernel<0><<<dim3(LQ / 64, DD / 64, BB), 256, 0, stream>>>((const float*)R1, outp,
                                                                   nullptr, nullptr);
}